// Round 2
// baseline (565.528 us; speedup 1.0000x reference)
//
#include <hip/hip_runtime.h>

#define N_NODES 100000
#define N_EDGES 1250000
#define D 64
#define ED 32

// 4 edges per wave-iteration: int4 index loads, early x-gathers, and 4
// independent FMA accumulator chains (ILP) instead of 1 serial chain.
__global__ void __launch_bounds__(256) edge_scatter_k(
    const float* __restrict__ x,
    const int* __restrict__ ei,     // [2][E] int32
    const float* __restrict__ ea,   // [E][32]
    const float* __restrict__ ew,   // [64][32]
    const float* __restrict__ eb,   // [64]
    float* __restrict__ agg,        // [N][64] (pre-zeroed; = d_out)
    float* __restrict__ deg)        // [N]     (pre-zeroed; in d_ws)
{
    const int lane = threadIdx.x & 63;
    const int wid  = blockIdx.x * (blockDim.x >> 6) + (threadIdx.x >> 6);
    const int nw   = gridDim.x * (blockDim.x >> 6);

    // lane d holds edge_w[d][0..31]
    float w[ED];
#pragma unroll
    for (int k = 0; k < ED; ++k) w[k] = ew[lane * ED + k];
    const float b = eb[lane];

    const int4* row4 = (const int4*)ei;             // rows  [E]
    const int4* col4 = (const int4*)(ei + N_EDGES); // cols  [E]
    const int NCH = N_EDGES / 4;                    // 312500, exact

    for (int ch = wid; ch < NCH; ch += nw) {
        const int4 r = row4[ch];
        const int4 c = col4[ch];

        // issue the 4 gathers early; they overlap the MLP below
        const float x0 = x[(size_t)r.x * D + lane];
        const float x1 = x[(size_t)r.y * D + lane];
        const float x2 = x[(size_t)r.z * D + lane];
        const float x3 = x[(size_t)r.w * D + lane];

        const float4* p0 = (const float4*)(ea + (size_t)(4 * ch) * ED);
        float a0 = b, a1 = b, a2 = b, a3 = b;
#pragma unroll
        for (int q = 0; q < ED / 4; ++q) {
            // 4 independent wave-uniform 16B loads, 4 independent FMA chains
            const float4 v0 = p0[q];
            const float4 v1 = p0[q + 8];
            const float4 v2 = p0[q + 16];
            const float4 v3 = p0[q + 24];
            a0 = fmaf(v0.x, w[4*q+0], a0); a0 = fmaf(v0.y, w[4*q+1], a0);
            a0 = fmaf(v0.z, w[4*q+2], a0); a0 = fmaf(v0.w, w[4*q+3], a0);
            a1 = fmaf(v1.x, w[4*q+0], a1); a1 = fmaf(v1.y, w[4*q+1], a1);
            a1 = fmaf(v1.z, w[4*q+2], a1); a1 = fmaf(v1.w, w[4*q+3], a1);
            a2 = fmaf(v2.x, w[4*q+0], a2); a2 = fmaf(v2.y, w[4*q+1], a2);
            a2 = fmaf(v2.z, w[4*q+2], a2); a2 = fmaf(v2.w, w[4*q+3], a2);
            a3 = fmaf(v3.x, w[4*q+0], a3); a3 = fmaf(v3.y, w[4*q+1], a3);
            a3 = fmaf(v3.z, w[4*q+2], a3); a3 = fmaf(v3.w, w[4*q+3], a3);
        }

        atomicAdd(&agg[(size_t)c.x * D + lane], a0 + x0);
        atomicAdd(&agg[(size_t)c.y * D + lane], a1 + x1);
        atomicAdd(&agg[(size_t)c.z * D + lane], a2 + x2);
        atomicAdd(&agg[(size_t)c.w * D + lane], a3 + x3);

        if (lane < 4) {
            const int cc = (lane == 0) ? c.x : (lane == 1) ? c.y
                         : (lane == 2) ? c.z : c.w;
            atomicAdd(&deg[cc], 1.0f);
        }
    }
}

// 2 nodes per wave-iteration, 2 independent dot chains.
__global__ void __launch_bounds__(256) node_linear_k(
    float* __restrict__ agg,        // [N][64] in, overwritten with result
    const float* __restrict__ deg,  // [N]
    const float* __restrict__ lw,   // [64][64]
    const float* __restrict__ lb)   // [64]
{
    const int lane = threadIdx.x & 63;
    const int wid  = blockIdx.x * (blockDim.x >> 6) + (threadIdx.x >> 6);
    const int nw   = gridDim.x * (blockDim.x >> 6);

    float w[D];
#pragma unroll
    for (int k = 0; k < D; ++k) w[k] = lw[lane * D + k];
    const float b = lb[lane];

    const int NP = N_NODES / 2;  // 50000, exact
    for (int p = wid; p < NP; p += nw) {
        const int n0 = 2 * p, n1 = 2 * p + 1;
        const float inv0 = 1.0f / fmaxf(deg[n0], 1.0f);
        const float inv1 = 1.0f / fmaxf(deg[n1], 1.0f);
        const float4* a4 = (const float4*)(agg + (size_t)n0 * D);
        float d0 = 0.0f, d1 = 0.0f;
#pragma unroll
        for (int q = 0; q < D / 4; ++q) {
            const float4 v0 = a4[q];
            const float4 v1 = a4[q + 16];
            d0 = fmaf(v0.x, w[4*q+0], d0); d0 = fmaf(v0.y, w[4*q+1], d0);
            d0 = fmaf(v0.z, w[4*q+2], d0); d0 = fmaf(v0.w, w[4*q+3], d0);
            d1 = fmaf(v1.x, w[4*q+0], d1); d1 = fmaf(v1.y, w[4*q+1], d1);
            d1 = fmaf(v1.z, w[4*q+2], d1); d1 = fmaf(v1.w, w[4*q+3], d1);
        }
        agg[(size_t)n0 * D + lane] = fmaf(inv0, d0, b);
        agg[(size_t)n1 * D + lane] = fmaf(inv1, d1, b);
    }
}

extern "C" void kernel_launch(void* const* d_in, const int* in_sizes, int n_in,
                              void* d_out, int out_size, void* d_ws, size_t ws_size,
                              hipStream_t stream) {
    const float* x  = (const float*)d_in[0];
    const int*   ei = (const int*)d_in[1];
    const float* ea = (const float*)d_in[2];
    const float* lw = (const float*)d_in[3];
    const float* lb = (const float*)d_in[4];
    const float* ew = (const float*)d_in[5];
    const float* eb = (const float*)d_in[6];

    float* agg = (float*)d_out;   // reuse output buffer as aggregation buffer
    float* deg = (float*)d_ws;    // N floats of scratch

    hipMemsetAsync(agg, 0, (size_t)N_NODES * D * sizeof(float), stream);
    hipMemsetAsync(deg, 0, (size_t)N_NODES * sizeof(float), stream);

    edge_scatter_k<<<2048, 256, 0, stream>>>(x, ei, ea, ew, eb, agg, deg);
    node_linear_k<<<1024, 256, 0, stream>>>(agg, deg, lw, lb);
}

// Round 3
// 397.771 us; speedup vs baseline: 1.4217x; 1.4217x over previous
//
#include <hip/hip_runtime.h>

#define N_NODES 100000
#define N_EDGES 1250000
#define D 64
#define ED 32
#define SCAN_BS 512
#define SCAN_NB 196   // ceil(100000/512)

// ---------------- CSR build ----------------

__global__ void __launch_bounds__(256) hist_k(const int* __restrict__ col,
                                              int* __restrict__ cnt) {
    int i = blockIdx.x * blockDim.x + threadIdx.x;
    int stride = gridDim.x * blockDim.x;
    const int4* c4 = (const int4*)col;
    for (int j = i; j < N_EDGES / 4; j += stride) {
        int4 c = c4[j];
        atomicAdd(&cnt[c.x], 1); atomicAdd(&cnt[c.y], 1);
        atomicAdd(&cnt[c.z], 1); atomicAdd(&cnt[c.w], 1);
    }
}

// per-block exclusive scan; block totals to bsum
__global__ void __launch_bounds__(SCAN_BS) scan_local_k(const int* __restrict__ cnt,
                                                        int* __restrict__ base,
                                                        int* __restrict__ bsum) {
    __shared__ int s[SCAN_BS];
    const int t = threadIdx.x;
    const int i = blockIdx.x * SCAN_BS + t;
    const int v = (i < N_NODES) ? cnt[i] : 0;
    s[t] = v;
    __syncthreads();
    for (int off = 1; off < SCAN_BS; off <<= 1) {
        int tv = (t >= off) ? s[t - off] : 0;
        __syncthreads();
        s[t] += tv;
        __syncthreads();
    }
    if (i < N_NODES) base[i] = s[t] - v;         // exclusive within block
    if (t == SCAN_BS - 1) bsum[blockIdx.x] = s[t];
}

__global__ void __launch_bounds__(256) scan_bsum_k(const int* __restrict__ bsum,
                                                   int* __restrict__ boff) {
    __shared__ int s[256];
    const int t = threadIdx.x;
    const int v = (t < SCAN_NB) ? bsum[t] : 0;
    s[t] = v;
    __syncthreads();
    for (int off = 1; off < 256; off <<= 1) {
        int tv = (t >= off) ? s[t - off] : 0;
        __syncthreads();
        s[t] += tv;
        __syncthreads();
    }
    if (t < SCAN_NB) boff[t] = s[t] - v;         // exclusive
}

__global__ void __launch_bounds__(SCAN_BS) scan_add_k(int* __restrict__ base,
                                                      const int* __restrict__ boff,
                                                      int* __restrict__ cursor) {
    const int i = blockIdx.x * SCAN_BS + threadIdx.x;
    if (i < N_NODES) {
        const int b = base[i] + boff[blockIdx.x];
        base[i] = b;
        cursor[i] = b;
    }
    if (i == 0) base[N_NODES] = N_EDGES;
}

__global__ void __launch_bounds__(256) scatter_k(const int* __restrict__ col,
                                                 int* __restrict__ cursor,
                                                 int* __restrict__ eid) {
    int i = blockIdx.x * blockDim.x + threadIdx.x;
    int stride = gridDim.x * blockDim.x;
    for (int e = i; e < N_EDGES; e += stride) {
        const int c = col[e];
        const int pos = atomicAdd(&cursor[c], 1);
        eid[pos] = e;
    }
}

// ---------------- weight folding: C = lw @ ew  [64][32], ebv = lw @ eb ----------------

__global__ void __launch_bounds__(256) combine_k(const float* __restrict__ lw,
                                                 const float* __restrict__ ew,
                                                 const float* __restrict__ eb,
                                                 float* __restrict__ Cmat,
                                                 float* __restrict__ ebv) {
    const int idx = blockIdx.x * blockDim.x + threadIdx.x;   // 8*256 = 2048
    if (idx < D * ED) {
        const int d = idx >> 5, j = idx & 31;
        float s = 0.f;
#pragma unroll
        for (int k = 0; k < D; ++k) s = fmaf(lw[d * D + k], ew[k * ED + j], s);
        Cmat[idx] = s;
    }
    if (idx < D) {
        float s = 0.f;
#pragma unroll
        for (int k = 0; k < D; ++k) s = fmaf(lw[idx * D + k], eb[k], s);
        ebv[idx] = s;
    }
}

// ---------------- aggregation (atomic-free, wave per node) ----------------

__global__ void __launch_bounds__(256) agg_k(const float* __restrict__ x,
                                             const int* __restrict__ row,
                                             const float* __restrict__ ea,
                                             const int* __restrict__ base,
                                             const int* __restrict__ eid,
                                             float* __restrict__ aggx,    // = d_out [N][64]
                                             float* __restrict__ agg32) { // [N][32]
    const int lane = threadIdx.x & 63;
    const int n = blockIdx.x * 4 + (threadIdx.x >> 6);
    if (n >= N_NODES) return;
    const int j0 = base[n], j1 = base[n + 1];

    float ax0 = 0.f, ax1 = 0.f, a0 = 0.f, a1 = 0.f;
    int j = j0;
    for (; j + 1 < j1; j += 2) {                 // 2 edges/iter: MLP-free, just adds
        const int e0 = eid[j], e1 = eid[j + 1];
        const int r0 = row[e0], r1 = row[e1];
        ax0 += x[(size_t)r0 * D + lane];
        ax1 += x[(size_t)r1 * D + lane];
        if (lane < ED) {
            a0 += ea[(size_t)e0 * ED + lane];
            a1 += ea[(size_t)e1 * ED + lane];
        }
    }
    if (j < j1) {
        const int e0 = eid[j];
        const int r0 = row[e0];
        ax0 += x[(size_t)r0 * D + lane];
        if (lane < ED) a0 += ea[(size_t)e0 * ED + lane];
    }
    aggx[(size_t)n * D + lane] = ax0 + ax1;
    if (lane < ED) agg32[(size_t)n * ED + lane] = a0 + a1;
}

// ---------------- epilogue: out = inv*(aggx@lw^T + agg32@C^T) + [deg>0]*ebv + lb ----------------

__global__ void __launch_bounds__(256) out_k(float* __restrict__ aggx,      // in/out = d_out
                                             const float* __restrict__ agg32,
                                             const int* __restrict__ base,
                                             const float* __restrict__ lw,
                                             const float* __restrict__ Cmat,
                                             const float* __restrict__ ebv,
                                             const float* __restrict__ lb) {
    const int lane = threadIdx.x & 63;
    const int wid  = blockIdx.x * (blockDim.x >> 6) + (threadIdx.x >> 6);
    const int nw   = gridDim.x * (blockDim.x >> 6);

    float w64[D];
#pragma unroll
    for (int k = 0; k < D; ++k) w64[k] = lw[lane * D + k];
    float c32[ED];
#pragma unroll
    for (int k = 0; k < ED; ++k) c32[k] = Cmat[lane * ED + k];
    const float eterm = ebv[lane];
    const float bias  = lb[lane];

    for (int n = wid; n < N_NODES; n += nw) {
        const int dg = base[n + 1] - base[n];
        const float inv = 1.f / fmaxf((float)dg, 1.f);
        const float4* ax = (const float4*)(aggx + (size_t)n * D);
        const float4* a3 = (const float4*)(agg32 + (size_t)n * ED);
        float d0 = 0.f, d1 = 0.f;
#pragma unroll
        for (int q = 0; q < D / 4; ++q) {
            const float4 v = ax[q];
            d0 = fmaf(v.x, w64[4*q+0], d0); d0 = fmaf(v.y, w64[4*q+1], d0);
            d0 = fmaf(v.z, w64[4*q+2], d0); d0 = fmaf(v.w, w64[4*q+3], d0);
        }
#pragma unroll
        for (int q = 0; q < ED / 4; ++q) {
            const float4 v = a3[q];
            d1 = fmaf(v.x, c32[4*q+0], d1); d1 = fmaf(v.y, c32[4*q+1], d1);
            d1 = fmaf(v.z, c32[4*q+2], d1); d1 = fmaf(v.w, c32[4*q+3], d1);
        }
        const float eb_on = (dg > 0) ? eterm : 0.f;
        aggx[(size_t)n * D + lane] = fmaf(inv, d0 + d1, eb_on + bias);
    }
}

// ---------------- fallback (small ws): R1 atomic version ----------------

__global__ void __launch_bounds__(256) edge_scatter_fb(
    const float* __restrict__ x, const int* __restrict__ ei,
    const float* __restrict__ ea, const float* __restrict__ ew,
    const float* __restrict__ eb, float* __restrict__ agg, float* __restrict__ deg) {
    const int lane = threadIdx.x & 63;
    const int wid  = blockIdx.x * (blockDim.x >> 6) + (threadIdx.x >> 6);
    const int nw   = gridDim.x * (blockDim.x >> 6);
    float w[ED];
#pragma unroll
    for (int k = 0; k < ED; ++k) w[k] = ew[lane * ED + k];
    const float b = eb[lane];
    for (int e = wid; e < N_EDGES; e += nw) {
        const int r = ei[e];
        const int c = ei[N_EDGES + e];
        const float4* ea4 = (const float4*)(ea + (size_t)e * ED);
        float acc = b;
#pragma unroll
        for (int q = 0; q < ED / 4; ++q) {
            float4 v = ea4[q];
            acc = fmaf(v.x, w[4*q+0], acc); acc = fmaf(v.y, w[4*q+1], acc);
            acc = fmaf(v.z, w[4*q+2], acc); acc = fmaf(v.w, w[4*q+3], acc);
        }
        acc += x[(size_t)r * D + lane];
        atomicAdd(&agg[(size_t)c * D + lane], acc);
        if (lane == 0) atomicAdd(&deg[c], 1.0f);
    }
}

__global__ void __launch_bounds__(256) node_linear_fb(
    float* __restrict__ agg, const float* __restrict__ deg,
    const float* __restrict__ lw, const float* __restrict__ lb) {
    const int lane = threadIdx.x & 63;
    const int wid  = blockIdx.x * (blockDim.x >> 6) + (threadIdx.x >> 6);
    const int nw   = gridDim.x * (blockDim.x >> 6);
    float w[D];
#pragma unroll
    for (int k = 0; k < D; ++k) w[k] = lw[lane * D + k];
    const float b = lb[lane];
    for (int n = wid; n < N_NODES; n += nw) {
        const float inv = 1.0f / fmaxf(deg[n], 1.0f);
        const float4* a4 = (const float4*)(agg + (size_t)n * D);
        float dot = 0.0f;
#pragma unroll
        for (int q = 0; q < D / 4; ++q) {
            float4 v = a4[q];
            dot = fmaf(v.x, w[4*q+0], dot); dot = fmaf(v.y, w[4*q+1], dot);
            dot = fmaf(v.z, w[4*q+2], dot); dot = fmaf(v.w, w[4*q+3], dot);
        }
        agg[(size_t)n * D + lane] = fmaf(inv, dot, b);
    }
}

// ---------------- launch ----------------

extern "C" void kernel_launch(void* const* d_in, const int* in_sizes, int n_in,
                              void* d_out, int out_size, void* d_ws, size_t ws_size,
                              hipStream_t stream) {
    const float* x  = (const float*)d_in[0];
    const int*   ei = (const int*)d_in[1];     // [2][E]: rows then cols
    const float* ea = (const float*)d_in[2];
    const float* lw = (const float*)d_in[3];
    const float* lb = (const float*)d_in[4];
    const float* ew = (const float*)d_in[5];
    const float* eb = (const float*)d_in[6];
    const int* row = ei;
    const int* col = ei + N_EDGES;

    // ws layout (bytes, 16-aligned)
    const size_t OFF_EID   = 0;                       // E ints      = 5,000,000
    const size_t OFF_CNT   = 5000000;                 // N ints      =   400,000
    const size_t OFF_BASE  = 5400000;                 // N+1 ints    (padded)
    const size_t OFF_BSUM  = 5800016;                 // 196 ints
    const size_t OFF_BOFF  = 5800800;                 // 196 ints
    const size_t OFF_CMAT  = 5801584;                 // 2048 floats
    const size_t OFF_EBV   = 5809776;                 // 64 floats
    const size_t OFF_AGG32 = 5810032;                 // N*32 floats = 12,800,000
    const size_t REQUIRED  = OFF_AGG32 + (size_t)N_NODES * ED * sizeof(float);

    char* ws = (char*)d_ws;
    float* aggx = (float*)d_out;

    if (ws_size >= REQUIRED) {
        int*   eid    = (int*)(ws + OFF_EID);
        int*   cnt    = (int*)(ws + OFF_CNT);     // reused as cursor
        int*   base   = (int*)(ws + OFF_BASE);
        int*   bsum   = (int*)(ws + OFF_BSUM);
        int*   boff   = (int*)(ws + OFF_BOFF);
        float* Cmat   = (float*)(ws + OFF_CMAT);
        float* ebv    = (float*)(ws + OFF_EBV);
        float* agg32  = (float*)(ws + OFF_AGG32);

        hipMemsetAsync(cnt, 0, (size_t)N_NODES * sizeof(int), stream);
        hist_k      <<<1024, 256, 0, stream>>>(col, cnt);
        scan_local_k<<<SCAN_NB, SCAN_BS, 0, stream>>>(cnt, base, bsum);
        scan_bsum_k <<<1, 256, 0, stream>>>(bsum, boff);
        scan_add_k  <<<SCAN_NB, SCAN_BS, 0, stream>>>(base, boff, cnt /*cursor*/);
        scatter_k   <<<1024, 256, 0, stream>>>(col, cnt /*cursor*/, eid);
        combine_k   <<<8, 256, 0, stream>>>(lw, ew, eb, Cmat, ebv);
        agg_k       <<<(N_NODES + 3) / 4, 256, 0, stream>>>(x, row, ea, base, eid, aggx, agg32);
        out_k       <<<2048, 256, 0, stream>>>(aggx, agg32, base, lw, Cmat, ebv, lb);
    } else {
        float* deg = (float*)d_ws;
        hipMemsetAsync(aggx, 0, (size_t)N_NODES * D * sizeof(float), stream);
        hipMemsetAsync(deg, 0, (size_t)N_NODES * sizeof(float), stream);
        edge_scatter_fb<<<2048, 256, 0, stream>>>(x, ei, ea, ew, eb, aggx, deg);
        node_linear_fb <<<1024, 256, 0, stream>>>(aggx, deg, lw, lb);
    }
}